// Round 2
// baseline (4096.168 us; speedup 1.0000x reference)
//
#include <hip/hip_runtime.h>
#include <hip/hip_bf16.h>
#include <math.h>

#define BB   8
#define SEQ  2048
#define HD   512
#define LAY  8
#define MD   32
#define NKB  256
#define LNEPS 1e-5f

__device__ __forceinline__ float b2f(__hip_bfloat16 v) { return __bfloat162float(v); }
__device__ __forceinline__ float geluf(float v) { return v * 0.5f * (1.f + erff(v * 0.70710678118654752f)); }

// dtype-agnostic input load: bf==1 -> bf16, bf==0 -> fp32
__device__ __forceinline__ float ldin(const void* p, size_t i, int bf) {
    if (bf) return __bfloat162float(((const __hip_bfloat16*)p)[i]);
    return ((const float*)p)[i];
}
__device__ __forceinline__ void stout(void* p, size_t i, float v, int bf) {
    if (bf) ((__hip_bfloat16*)p)[i] = __float2bfloat16(v);
    else    ((float*)p)[i] = v;
}

// ---------------- dtype probe: ln_g is all ones ----------------
// fp32 1.0 = 0x3F800000 ; bf16 pair (1.0,1.0) = 0x3F803F80
__global__ void k_flag(const unsigned int* __restrict__ lng_bits, int* __restrict__ flag) {
    if (threadIdx.x == 0 && blockIdx.x == 0)
        *flag = (lng_bits[0] == 0x3F803F80u) ? 1 : 0;
}

// ---------------- twiddle table: trig[s][m] = (cos, sin) of 2*pi*m*s/SEQ ----------------
__global__ void k_trig(float* __restrict__ trig) {
    int idx = blockIdx.x * 256 + threadIdx.x;        // SEQ*MD = 65536
    if (idx >= SEQ * MD) return;
    int s = idx / MD, m = idx % MD;
    int phase = (m * s) & (SEQ - 1);
    float ang = (float)phase * (6.283185307179586f / (float)SEQ);
    trig[idx * 2]     = cosf(ang);
    trig[idx * 2 + 1] = sinf(ang);
}

// ---------------- transpose conv_w [L][ko][hi] -> cwT [L][hi][ko] (fp32) ----------------
__global__ void k_cwt(const void* __restrict__ cw, float* __restrict__ cwT, const int* __restrict__ flag) {
    int bf = *flag;
    int idx = blockIdx.x * 256 + threadIdx.x;        // LAY*HD*HD = 2097152
    int l = idx >> 18;
    int r = idx & 262143;
    int hi = r >> 9;
    int ko = r & 511;
    cwT[idx] = ldin(cw, (size_t)(l << 18) + (ko << 9) + hi, bf);
}

// ---------------- generic [R][C] -> fp32 [C][R] transpose ----------------
__global__ void k_tr(const void* __restrict__ src, float* __restrict__ dst, int log2R, int C, int n,
                     const int* __restrict__ flag) {
    int bf = *flag;
    int idx = blockIdx.x * 256 + threadIdx.x;
    if (idx >= n) return;
    int R = 1 << log2R;
    int r = idx & (R - 1);
    int c = idx >> log2R;
    dst[idx] = ldin(src, (size_t)r * C + c, bf);
}

// ---------------- input projection: h[b,s,j] = x[b,s]*in_w[j] + in_b[j] ----------------
__global__ void k_in(const void* __restrict__ x, const void* __restrict__ in_w, const void* __restrict__ in_b,
                     float* __restrict__ h, const int* __restrict__ flag) {
    int bf = *flag;
    int idx = blockIdx.x * 256 + threadIdx.x;        // BB*SEQ*HD = 8388608
    int j = idx & 511;
    int bs = idx >> 9;
    h[idx] = ldin(x, bs, bf) * ldin(in_w, j, bf) + ldin(in_b, j, bf);
}

// ---------------- forward DFT (32 modes), s-chunked partials ----------------
// grid (sc=16, ht=2, b=8), block 256. Xp[sc][b][m][h][2]
__global__ __launch_bounds__(256) void k_dft(const float* __restrict__ h, const float* __restrict__ trig,
                                             float* __restrict__ Xp) {
    int sc = blockIdx.x, ht = blockIdx.y, b = blockIdx.z;
    int t = threadIdx.x;
    int hidx = ht * 256 + t;
    int s0 = sc * 128;
    __shared__ float2 tg[128 * 32];
    const float2* trig2 = (const float2*)trig;
    for (int e = t; e < 128 * 32; e += 256) tg[e] = trig2[s0 * 32 + e];
    __syncthreads();
    float ar[32], ai[32];
#pragma unroll
    for (int m = 0; m < 32; m++) { ar[m] = 0.f; ai[m] = 0.f; }
    const float* hp = h + ((size_t)b * SEQ + s0) * HD + hidx;
    for (int i = 0; i < 128; i++) {
        float v = hp[(size_t)i * HD];
#pragma unroll
        for (int m = 0; m < 32; m++) {
            float2 cs = tg[i * 32 + m];
            ar[m] += v * cs.x;      // e^{-i theta}: cos
            ai[m] -= v * cs.y;      // -sin
        }
    }
    float* outp = Xp + (size_t)(sc * 8 + b) * 32768 + hidx * 2;
#pragma unroll
    for (int m = 0; m < 32; m++) {
        outp[m * 1024]     = ar[m];
        outp[m * 1024 + 1] = ai[m];
    }
}

// reduce 16 partials -> Xft[b][m][h][2]
__global__ void k_dft_red(const float* __restrict__ Xp, float* __restrict__ Xft) {
    int idx = blockIdx.x * 256 + threadIdx.x;        // 262144
    float s = 0.f;
    for (int c = 0; c < 16; c++) s += Xp[(size_t)c * 262144 + idx];
    Xft[idx] = s;
}

// ---------------- per-mode complex mixing: spec[b,m,k] = sum_h Xft[b,m,h] * (fwr+i fwi)[l,m,h,k]
// grid (kt=8, m=32), block 256 (64 k-lanes x 4 h-groups)
__global__ __launch_bounds__(256) void k_mix(const float* __restrict__ Xft,
                                             const void* __restrict__ fwr, const void* __restrict__ fwi,
                                             float* __restrict__ spec, int l, const int* __restrict__ flag) {
    int bf = *flag;
    int kt = blockIdx.x;
    int m  = blockIdx.y;
    int t = threadIdx.x;
    int kk = t & 63, hg = t >> 6;
    int k = kt * 64 + kk;
    __shared__ float xs[8192];                        // [b][h][2] = b*1024 + h*2 + ri
    for (int e = t; e < 8192; e += 256) {
        int b = e >> 10, r = e & 1023;
        xs[b * 1024 + r] = Xft[(size_t)(b * 32 + m) * 1024 + r];
    }
    __syncthreads();
    float ar[8], ai[8];
#pragma unroll
    for (int b = 0; b < 8; b++) { ar[b] = 0.f; ai[b] = 0.f; }
    size_t wbase = (size_t)(l * 32 + m) * 262144 + k;
    if (bf) {
        const __hip_bfloat16* fr = (const __hip_bfloat16*)fwr;
        const __hip_bfloat16* fi = (const __hip_bfloat16*)fwi;
        for (int hh = hg; hh < 512; hh += 4) {
            float wr = b2f(fr[wbase + (size_t)hh * 512]);
            float wi = b2f(fi[wbase + (size_t)hh * 512]);
#pragma unroll
            for (int b = 0; b < 8; b++) {
                float xr = xs[b * 1024 + hh * 2];
                float xi = xs[b * 1024 + hh * 2 + 1];
                ar[b] += xr * wr - xi * wi;
                ai[b] += xr * wi + xi * wr;
            }
        }
    } else {
        const float* fr = (const float*)fwr;
        const float* fi = (const float*)fwi;
        for (int hh = hg; hh < 512; hh += 4) {
            float wr = fr[wbase + (size_t)hh * 512];
            float wi = fi[wbase + (size_t)hh * 512];
#pragma unroll
            for (int b = 0; b < 8; b++) {
                float xr = xs[b * 1024 + hh * 2];
                float xi = xs[b * 1024 + hh * 2 + 1];
                ar[b] += xr * wr - xi * wi;
                ai[b] += xr * wi + xi * wr;
            }
        }
    }
    __shared__ float red[4096];                       // [t][16]
#pragma unroll
    for (int b = 0; b < 8; b++) { red[t * 16 + b * 2] = ar[b]; red[t * 16 + b * 2 + 1] = ai[b]; }
    __syncthreads();
    if (hg == 0) {
#pragma unroll
        for (int b = 0; b < 8; b++) {
            float sr = 0.f, si = 0.f;
#pragma unroll
            for (int g = 0; g < 4; g++) {
                sr += red[(g * 64 + kk) * 16 + b * 2];
                si += red[(g * 64 + kk) * 16 + b * 2 + 1];
            }
            spec[(size_t)(b * 32 + m) * 1024 + k * 2]     = sr;
            spec[(size_t)(b * 32 + m) * 1024 + k * 2 + 1] = si;
        }
    }
}

// ---------------- conv GEMM (128x128 tile) + inverse-DFT(32 modes) + bias -> y ----------------
// grid (mt=128, nt=4), block 256 (tx=n 16, ty=m 16), 8x8 micro-tile
__global__ __launch_bounds__(256) void k_conv(const float* __restrict__ h, const float* __restrict__ cwT,
                                              const float* __restrict__ spec, const float* __restrict__ trig,
                                              const void* __restrict__ cb, float* __restrict__ y, int l,
                                              const int* __restrict__ flag) {
    int bf = *flag;
    __shared__ float smem[16384];                     // 64 KB, reused
    int mt = blockIdx.x, nt = blockIdx.y;
    int t = threadIdx.x;
    int tx = t & 15, ty = t >> 4;
    int row0 = mt * 128;
    int b = row0 >> 11;
    int s0 = row0 & 2047;
    int n0 = nt * 128;
    float acc[8][8];
#pragma unroll
    for (int i = 0; i < 8; i++)
#pragma unroll
        for (int j = 0; j < 8; j++) acc[i][j] = 0.f;

    float* As = smem;                                 // [8][132]
    float* Bs = smem + 1056;                          // [8][128]
    const float* Ag = h + (size_t)row0 * HD;
    const float* Bg = cwT + (size_t)l * 262144;
    for (int k0 = 0; k0 < 512; k0 += 8) {
        for (int e = t; e < 1024; e += 256) {
            int mm = e >> 3, kk = e & 7;
            As[kk * 132 + mm] = Ag[(size_t)mm * HD + k0 + kk];
        }
        for (int e = t; e < 1024; e += 256) {
            int kk = e >> 7, nn = e & 127;
            Bs[kk * 128 + nn] = Bg[(size_t)(k0 + kk) * HD + n0 + nn];
        }
        __syncthreads();
#pragma unroll
        for (int kk = 0; kk < 8; kk++) {
            float a[8], bv[8];
#pragma unroll
            for (int i = 0; i < 8; i++) a[i] = As[kk * 132 + ty * 8 + i];
#pragma unroll
            for (int j = 0; j < 8; j++) bv[j] = Bs[kk * 128 + tx * 8 + j];
#pragma unroll
            for (int i = 0; i < 8; i++)
#pragma unroll
                for (int j = 0; j < 8; j++) acc[i][j] += a[i] * bv[j];
        }
        __syncthreads();
    }

    // stage spectral slice + twiddles (prescaled by 2/SEQ)
    float* spR  = smem;                               // [32][128]
    float* spI  = smem + 4096;
    float* tgsC = smem + 8192;
    float* tgsS = smem + 12288;
    const float SCL = 2.f / (float)SEQ;
    for (int e = t; e < 4096; e += 256) {
        int m = e >> 7, nn = e & 127;
        size_t gi = (size_t)(b * 32 + m) * 1024 + (n0 + nn) * 2;
        spR[e] = spec[gi];
        spI[e] = spec[gi + 1];
    }
    for (int e = t; e < 4096; e += 256) {
        int m = e >> 7, sl = e & 127;
        size_t gi = (size_t)((s0 + sl) * 32 + m) * 2;
        tgsC[e] = trig[gi] * SCL;
        tgsS[e] = trig[gi + 1] * SCL;
    }
    __syncthreads();

    for (int m = 1; m < 32; m++) {
        float cv[8], sv[8], xr[8], xi[8];
#pragma unroll
        for (int i = 0; i < 8; i++) { cv[i] = tgsC[m * 128 + ty * 8 + i]; sv[i] = tgsS[m * 128 + ty * 8 + i]; }
#pragma unroll
        for (int j = 0; j < 8; j++) { xr[j] = spR[m * 128 + tx * 8 + j]; xi[j] = spI[m * 128 + tx * 8 + j]; }
#pragma unroll
        for (int i = 0; i < 8; i++)
#pragma unroll
            for (int j = 0; j < 8; j++) {
                acc[i][j] += cv[i] * xr[j];
                acc[i][j] -= sv[i] * xi[j];
            }
    }
    const float inv = 1.f / (float)SEQ;
#pragma unroll
    for (int j = 0; j < 8; j++) {
        int n = n0 + tx * 8 + j;
        float dcb = spR[tx * 8 + j] * inv + ldin(cb, l * HD + n, bf);
#pragma unroll
        for (int i = 0; i < 8; i++) {
            int r = row0 + ty * 8 + i;
            y[(size_t)r * HD + n] = acc[i][j] + dcb;
        }
    }
}

// ---------------- LayerNorm + affine + residual (in place on h) ----------------
__global__ __launch_bounds__(256) void k_ln(const float* __restrict__ y, const void* __restrict__ g,
                                            const void* __restrict__ bb, float* __restrict__ h, int l,
                                            const int* __restrict__ flag) {
    int bf = *flag;
    int row = blockIdx.x;
    int t = threadIdx.x;
    const float* yr = y + (size_t)row * HD;
    float v0 = yr[t], v1 = yr[t + 256];
    float s = v0 + v1, q = v0 * v0 + v1 * v1;
#pragma unroll
    for (int o = 32; o > 0; o >>= 1) { s += __shfl_down(s, o); q += __shfl_down(q, o); }
    __shared__ float sm[8];
    __shared__ float mv[2];
    int wid = t >> 6;
    if ((t & 63) == 0) { sm[wid] = s; sm[wid + 4] = q; }
    __syncthreads();
    if (t == 0) {
        float S = sm[0] + sm[1] + sm[2] + sm[3];
        float Q = sm[4] + sm[5] + sm[6] + sm[7];
        float mu = S * (1.f / (float)HD);
        float var = Q * (1.f / (float)HD) - mu * mu;
        mv[0] = mu; mv[1] = rsqrtf(var + LNEPS);
    }
    __syncthreads();
    float mu = mv[0], rs = mv[1];
    float* hr = h + (size_t)row * HD;
    hr[t]       = (v0 - mu) * rs * ldin(g, l * HD + t, bf)       + ldin(bb, l * HD + t, bf)       + hr[t];
    hr[t + 256] = (v1 - mu) * rs * ldin(g, l * HD + t + 256, bf) + ldin(bb, l * HD + t + 256, bf) + hr[t + 256];
}

// ---------------- fused output projection 512->256->128->1 over 16 rows/block ----------------
__global__ __launch_bounds__(256) void k_proj(const float* __restrict__ h,
                                              const float* __restrict__ w1T, const void* __restrict__ b1,
                                              const float* __restrict__ w2T, const void* __restrict__ b2,
                                              const void* __restrict__ w3, const void* __restrict__ b3,
                                              void* __restrict__ out, const int* __restrict__ flag) {
    int bf = *flag;
    int row0 = blockIdx.x * 16;
    int t = threadIdx.x;
    __shared__ float hs[512 * 16];                    // [j][sl]
    __shared__ float o1s[256 * 16];
    __shared__ float o2s[128 * 16];
    for (int e = t; e < 16 * 512; e += 256) {
        int sl = e >> 9, j = e & 511;
        hs[j * 16 + sl] = h[(size_t)(row0 + sl) * HD + j];
    }
    __syncthreads();
    float acc[16];
#pragma unroll
    for (int i = 0; i < 16; i++) acc[i] = 0.f;
    for (int j = 0; j < 512; j++) {
        float w = w1T[j * 256 + t];
#pragma unroll
        for (int sl = 0; sl < 16; sl++) acc[sl] += hs[j * 16 + sl] * w;
    }
    float bb1 = ldin(b1, t, bf);
#pragma unroll
    for (int sl = 0; sl < 16; sl++) o1s[t * 16 + sl] = geluf(acc[sl] + bb1);
    __syncthreads();
    if (t < 128) {
        float a2[16];
#pragma unroll
        for (int i = 0; i < 16; i++) a2[i] = 0.f;
        for (int j = 0; j < 256; j++) {
            float w = w2T[j * 128 + t];
#pragma unroll
            for (int sl = 0; sl < 16; sl++) a2[sl] += o1s[j * 16 + sl] * w;
        }
        float bb2 = ldin(b2, t, bf);
#pragma unroll
        for (int sl = 0; sl < 16; sl++) o2s[t * 16 + sl] = geluf(a2[sl] + bb2);
    }
    __syncthreads();
    if (t < 16) {
        float sum = 0.f;
        for (int j = 0; j < 128; j++) sum += o2s[j * 16 + t] * ldin(w3, j, bf);
        stout(out, row0 + t, sum + ldin(b3, 0, bf), bf);
    }
}

// ---------------- gf = mean over S ----------------
__global__ void k_zero(float* p, int n) {
    int i = blockIdx.x * 256 + threadIdx.x;
    if (i < n) p[i] = 0.f;
}

__global__ __launch_bounds__(512) void k_gf(const float* __restrict__ h, float* __restrict__ gf) {
    int sc = blockIdx.x, b = blockIdx.y;
    int j = threadIdx.x;
    const float* p = h + ((size_t)b * SEQ + sc * 128) * HD + j;
    float s = 0.f;
    for (int i = 0; i < 128; i++) s += p[(size_t)i * HD];
    atomicAdd(&gf[b * HD + j], s * (1.f / (float)SEQ));
}

// ---------------- cryptanalytic head ----------------
__global__ __launch_bounds__(512) void k_head(const float* __restrict__ gf,
                                              const float* __restrict__ h1T, const void* __restrict__ h1b,
                                              const float* __restrict__ h2T, const void* __restrict__ h2b,
                                              void* __restrict__ out, const int* __restrict__ flag) {
    int bf = *flag;
    int b = blockIdx.x;
    int t = threadIdx.x;
    __shared__ float gs[512];
    __shared__ float ks[512];
    gs[t] = gf[b * HD + t];
    __syncthreads();
    float a = 0.f;
    for (int j = 0; j < 512; j++) a += gs[j] * h1T[j * 512 + t];
    ks[t] = geluf(a + ldin(h1b, t, bf));
    __syncthreads();
    if (t < 256) {
        float s = 0.f;
        for (int j = 0; j < 512; j++) s += ks[j] * h2T[j * 256 + t];
        s += ldin(h2b, t, bf);
        stout(out, BB * SEQ + b * NKB + t, 1.f / (1.f + expf(-s)), bf);
    }
}

extern "C" void kernel_launch(void* const* d_in, const int* in_sizes, int n_in,
                              void* d_out, int out_size, void* d_ws, size_t ws_size,
                              hipStream_t stream) {
    const void* x    = d_in[0];
    const void* in_w = d_in[1];
    const void* in_b = d_in[2];
    const void* fwr  = d_in[3];
    const void* fwi  = d_in[4];
    const void* cw   = d_in[5];
    const void* cb   = d_in[6];
    const void* lng  = d_in[7];
    const void* lnb  = d_in[8];
    const void* w1   = d_in[9];
    const void* b1   = d_in[10];
    const void* w2   = d_in[11];
    const void* b2   = d_in[12];
    const void* w3   = d_in[13];
    const void* b3   = d_in[14];
    const void* h1w  = d_in[15];
    const void* h1b  = d_in[16];
    const void* h2w  = d_in[17];
    const void* h2b  = d_in[18];

    float* ws   = (float*)d_ws;
    float* trig = ws;                       // 131072
    float* h    = trig + 131072;            // 8388608
    float* y    = h + 8388608;              // 8388608 (Xp aliases y: 4194304 used)
    float* Xp   = y;
    float* cwT  = y + 8388608;              // 2097152
    float* Xft  = cwT + 2097152;            // 262144
    float* spec = Xft + 262144;             // 262144
    float* gf   = spec + 262144;            // 4096
    float* w1T  = gf + 4096;                // 131072
    float* w2T  = w1T + 131072;             // 32768
    float* h1T  = w2T + 32768;              // 262144
    float* h2T  = h1T + 262144;             // 131072
    int*   flag = (int*)(h2T + 131072);     // 1

    k_flag<<<1, 1, 0, stream>>>((const unsigned int*)lng, flag);
    k_trig<<<256, 256, 0, stream>>>(trig);
    k_cwt<<<8192, 256, 0, stream>>>(cw, cwT, flag);
    k_tr<<<512, 256, 0, stream>>>(w1, w1T, 8, 512, 131072, flag);
    k_tr<<<128, 256, 0, stream>>>(w2, w2T, 7, 256, 32768, flag);
    k_tr<<<1024, 256, 0, stream>>>(h1w, h1T, 9, 512, 262144, flag);
    k_tr<<<512, 256, 0, stream>>>(h2w, h2T, 8, 512, 131072, flag);
    k_in<<<32768, 256, 0, stream>>>(x, in_w, in_b, h, flag);

    for (int l = 0; l < LAY; l++) {
        k_dft<<<dim3(16, 2, 8), 256, 0, stream>>>(h, trig, Xp);
        k_dft_red<<<1024, 256, 0, stream>>>(Xp, Xft);
        k_mix<<<dim3(8, 32), 256, 0, stream>>>(Xft, fwr, fwi, spec, l, flag);
        k_conv<<<dim3(128, 4), 256, 0, stream>>>(h, cwT, spec, trig, cb, y, l, flag);
        k_ln<<<16384, 256, 0, stream>>>(y, lng, lnb, h, l, flag);
    }

    k_zero<<<16, 256, 0, stream>>>(gf, 4096);
    k_gf<<<dim3(16, 8), 512, 0, stream>>>(h, gf);
    k_proj<<<1024, 256, 0, stream>>>(h, w1T, b1, w2T, b2, w3, b3, d_out, flag);
    k_head<<<8, 512, 0, stream>>>(gf, h1T, h1b, h2T, h2b, d_out, flag);
}

// Round 3
// 2162.026 us; speedup vs baseline: 1.8946x; 1.8946x over previous
//
#include <hip/hip_runtime.h>
#include <hip/hip_bf16.h>
#include <math.h>

#define BB   8
#define SEQ  2048
#define HD   512
#define LAY  8
#define MD   32
#define NKB  256
#define LNEPS 1e-5f

typedef __attribute__((ext_vector_type(8))) short v8s;
typedef __attribute__((ext_vector_type(4))) float v4f;

__device__ __forceinline__ float b2f(__hip_bfloat16 v) { return __bfloat162float(v); }
__device__ __forceinline__ float geluf(float v) { return v * 0.5f * (1.f + erff(v * 0.70710678118654752f)); }

// dtype-agnostic input load: bf==1 -> bf16, bf==0 -> fp32
__device__ __forceinline__ float ldin(const void* p, size_t i, int bf) {
    if (bf) return __bfloat162float(((const __hip_bfloat16*)p)[i]);
    return ((const float*)p)[i];
}
__device__ __forceinline__ void stout(void* p, size_t i, float v, int bf) {
    if (bf) ((__hip_bfloat16*)p)[i] = __float2bfloat16(v);
    else    ((float*)p)[i] = v;
}

__device__ __forceinline__ void gl2lds16(const void* g, void* l) {
    __builtin_amdgcn_global_load_lds((__attribute__((address_space(1))) void*)g,
                                     (__attribute__((address_space(3))) void*)l, 16, 0, 0);
}

// ---------------- dtype probe: ln_g is all ones ----------------
__global__ void k_flag(const unsigned int* __restrict__ lng_bits, int* __restrict__ flag) {
    if (threadIdx.x == 0 && blockIdx.x == 0)
        *flag = (lng_bits[0] == 0x3F803F80u) ? 1 : 0;
}

// ---------------- twiddle table: trig[s][m] = (cos, sin) of 2*pi*m*s/SEQ ----------------
__global__ void k_trig(float* __restrict__ trig) {
    int idx = blockIdx.x * 256 + threadIdx.x;        // SEQ*MD = 65536
    if (idx >= SEQ * MD) return;
    int s = idx / MD, m = idx % MD;
    int phase = (m * s) & (SEQ - 1);
    float ang = (float)phase * (6.283185307179586f / (float)SEQ);
    trig[idx * 2]     = cosf(ang);
    trig[idx * 2 + 1] = sinf(ang);
}

// ---------------- inverse-DFT operator columns: T2[s][64] bf16 ----------------
__global__ void k_t2(__hip_bfloat16* __restrict__ T2) {
    int idx = blockIdx.x * 256 + threadIdx.x;        // 2048*64 = 131072
    int s = idx >> 6, j = idx & 63;
    int m = j >> 1;
    float v;
    if (j == 0)      v = 1.f / (float)SEQ;
    else if (j == 1) v = 0.f;
    else {
        int phase = (m * s) & (SEQ - 1);
        float ang = (float)phase * (6.283185307179586f / (float)SEQ);
        v = (j & 1) ? (-2.f / (float)SEQ) * sinf(ang) : (2.f / (float)SEQ) * cosf(ang);
    }
    T2[idx] = __float2bfloat16(v);
}

// ---------------- conv_w -> bf16 (identity layout [l][n][k]) ----------------
__global__ void k_cwbf(const void* __restrict__ cw, __hip_bfloat16* __restrict__ dst,
                       const int* __restrict__ flag) {
    int bf = *flag;
    int idx = blockIdx.x * 256 + threadIdx.x;        // 2097152
    dst[idx] = __float2bfloat16(ldin(cw, idx, bf));
}

// ---------------- generic [R][C] -> fp32 [C][R] transpose ----------------
__global__ void k_tr(const void* __restrict__ src, float* __restrict__ dst, int log2R, int C, int n,
                     const int* __restrict__ flag) {
    int bf = *flag;
    int idx = blockIdx.x * 256 + threadIdx.x;
    if (idx >= n) return;
    int R = 1 << log2R;
    int r = idx & (R - 1);
    int c = idx >> log2R;
    dst[idx] = ldin(src, (size_t)r * C + c, bf);
}

// ---------------- input projection ----------------
__global__ void k_in(const void* __restrict__ x, const void* __restrict__ in_w, const void* __restrict__ in_b,
                     float* __restrict__ h, __hip_bfloat16* __restrict__ hbf, const int* __restrict__ flag) {
    int bf = *flag;
    int idx = blockIdx.x * 256 + threadIdx.x;        // 8388608
    int j = idx & 511;
    int bs = idx >> 9;
    float v = ldin(x, bs, bf) * ldin(in_w, j, bf) + ldin(in_b, j, bf);
    h[idx] = v;
    hbf[idx] = __float2bfloat16(v);
}

// ---------------- forward DFT (32 modes), s-chunked partials ----------------
__global__ __launch_bounds__(256) void k_dft(const float* __restrict__ h, const float* __restrict__ trig,
                                             float* __restrict__ Xp) {
    int sc = blockIdx.x, ht = blockIdx.y, b = blockIdx.z;
    int t = threadIdx.x;
    int hidx = ht * 256 + t;
    int s0 = sc * 128;
    __shared__ float2 tg[128 * 32];
    const float2* trig2 = (const float2*)trig;
    for (int e = t; e < 128 * 32; e += 256) tg[e] = trig2[s0 * 32 + e];
    __syncthreads();
    float ar[32], ai[32];
#pragma unroll
    for (int m = 0; m < 32; m++) { ar[m] = 0.f; ai[m] = 0.f; }
    const float* hp = h + ((size_t)b * SEQ + s0) * HD + hidx;
    for (int i = 0; i < 128; i++) {
        float v = hp[(size_t)i * HD];
#pragma unroll
        for (int m = 0; m < 32; m++) {
            float2 cs = tg[i * 32 + m];
            ar[m] += v * cs.x;
            ai[m] -= v * cs.y;
        }
    }
    float* outp = Xp + (size_t)(sc * 8 + b) * 32768 + hidx * 2;
#pragma unroll
    for (int m = 0; m < 32; m++) {
        outp[m * 1024]     = ar[m];
        outp[m * 1024 + 1] = ai[m];
    }
}

__global__ void k_dft_red(const float* __restrict__ Xp, float* __restrict__ Xft) {
    int idx = blockIdx.x * 256 + threadIdx.x;        // 262144
    float s = 0.f;
    for (int c = 0; c < 16; c++) s += Xp[(size_t)c * 262144 + idx];
    Xft[idx] = s;
}

// ---------------- per-mode complex mixing -> spec2 bf16 [b][n][2m|2m+1] ----------------
__global__ __launch_bounds__(256) void k_mix(const float* __restrict__ Xft,
                                             const void* __restrict__ fwr, const void* __restrict__ fwi,
                                             __hip_bfloat16* __restrict__ spec2, int l,
                                             const int* __restrict__ flag) {
    int bf = *flag;
    int kt = blockIdx.x;
    int m  = blockIdx.y;
    int t = threadIdx.x;
    int kk = t & 63, hg = t >> 6;
    int k = kt * 64 + kk;
    __shared__ float xs[8192];
    for (int e = t; e < 8192; e += 256) {
        int b = e >> 10, r = e & 1023;
        xs[b * 1024 + r] = Xft[(size_t)(b * 32 + m) * 1024 + r];
    }
    __syncthreads();
    float ar[8], ai[8];
#pragma unroll
    for (int b = 0; b < 8; b++) { ar[b] = 0.f; ai[b] = 0.f; }
    size_t wbase = (size_t)(l * 32 + m) * 262144 + k;
    if (bf) {
        const __hip_bfloat16* fr = (const __hip_bfloat16*)fwr;
        const __hip_bfloat16* fi = (const __hip_bfloat16*)fwi;
        for (int hh = hg; hh < 512; hh += 4) {
            float wr = b2f(fr[wbase + (size_t)hh * 512]);
            float wi = b2f(fi[wbase + (size_t)hh * 512]);
#pragma unroll
            for (int b = 0; b < 8; b++) {
                float xr = xs[b * 1024 + hh * 2];
                float xi = xs[b * 1024 + hh * 2 + 1];
                ar[b] += xr * wr - xi * wi;
                ai[b] += xr * wi + xi * wr;
            }
        }
    } else {
        const float* fr = (const float*)fwr;
        const float* fi = (const float*)fwi;
        for (int hh = hg; hh < 512; hh += 4) {
            float wr = fr[wbase + (size_t)hh * 512];
            float wi = fi[wbase + (size_t)hh * 512];
#pragma unroll
            for (int b = 0; b < 8; b++) {
                float xr = xs[b * 1024 + hh * 2];
                float xi = xs[b * 1024 + hh * 2 + 1];
                ar[b] += xr * wr - xi * wi;
                ai[b] += xr * wi + xi * wr;
            }
        }
    }
    __shared__ float red[4096];
#pragma unroll
    for (int b = 0; b < 8; b++) { red[t * 16 + b * 2] = ar[b]; red[t * 16 + b * 2 + 1] = ai[b]; }
    __syncthreads();
    if (hg == 0) {
#pragma unroll
        for (int b = 0; b < 8; b++) {
            float sr = 0.f, si = 0.f;
#pragma unroll
            for (int g = 0; g < 4; g++) {
                sr += red[(g * 64 + kk) * 16 + b * 2];
                si += red[(g * 64 + kk) * 16 + b * 2 + 1];
            }
            size_t o = ((size_t)(b * 512 + k) << 6) + 2 * m;
            spec2[o]     = __float2bfloat16(sr);
            spec2[o + 1] = __float2bfloat16(si);
        }
    }
}

// ---------------- MFMA GEMM: y[16384x512] = A_ext[16384x576] * B_ext[576x512] + cb ----------------
// A cols 0..511 = h_bf, 512..575 = T2[s]; B rows 0..511 = cw[l][n][k], 512..575 = spec2[b][n][j]
// 128x128 tile, BK=32, 4 waves, each wave 64x64 (4x4 of 16x16x32 MFMA)
__global__ __launch_bounds__(256) void k_gemm(const __hip_bfloat16* __restrict__ hbf,
                                              const __hip_bfloat16* __restrict__ cwbf,
                                              const __hip_bfloat16* __restrict__ T2,
                                              const __hip_bfloat16* __restrict__ spec2,
                                              const void* __restrict__ cb,
                                              __hip_bfloat16* __restrict__ ybf,
                                              int l, const int* __restrict__ flag) {
    int bfv = *flag;
    __shared__ __hip_bfloat16 Als[128 * 32];
    __shared__ __hip_bfloat16 Bls[128 * 32];
    int t = threadIdx.x;
    int lane = t & 63, wv = t >> 6;
    int wr = wv >> 1, wc = wv & 1;
    int ln15 = lane & 15, quad = lane >> 4;
    int row0 = blockIdx.x * 128, n0 = blockIdx.y * 128;
    int b = row0 >> 11;
    int s0 = row0 & 2047;

    v4f acc[16];
#pragma unroll
    for (int i = 0; i < 16; i++) acc[i] = (v4f){0.f, 0.f, 0.f, 0.f};

    const __hip_bfloat16* cwl = cwbf + (size_t)l * 262144;
    for (int kc = 0; kc < 18; kc++) {
        int k0 = kc * 32;
#pragma unroll
        for (int p = 0; p < 2; p++) {
            int i = p * 256 + t;
            int row = i >> 2, kq = (i & 3) * 8;
            const __hip_bfloat16 *asrc, *bsrc;
            if (k0 < 512) {
                asrc = hbf + (size_t)(row0 + row) * 512 + k0 + kq;
                bsrc = cwl + (size_t)(n0 + row) * 512 + k0 + kq;
            } else {
                asrc = T2 + (size_t)(s0 + row) * 64 + (k0 - 512) + kq;
                bsrc = spec2 + (size_t)(b * 512 + n0 + row) * 64 + (k0 - 512) + kq;
            }
            gl2lds16(asrc, &Als[(size_t)(p * 256 + wv * 64) * 8]);
            gl2lds16(bsrc, &Bls[(size_t)(p * 256 + wv * 64) * 8]);
        }
        __syncthreads();
        v8s af[4], bfr[4];
#pragma unroll
        for (int i = 0; i < 4; i++)
            af[i] = *(const v8s*)&Als[(wr * 64 + i * 16 + ln15) * 32 + quad * 8];
#pragma unroll
        for (int j = 0; j < 4; j++)
            bfr[j] = *(const v8s*)&Bls[(wc * 64 + j * 16 + ln15) * 32 + quad * 8];
#pragma unroll
        for (int i = 0; i < 4; i++)
#pragma unroll
            for (int j = 0; j < 4; j++)
                acc[i * 4 + j] = __builtin_amdgcn_mfma_f32_16x16x32_bf16(af[i], bfr[j], acc[i * 4 + j], 0, 0, 0);
        __syncthreads();
    }
#pragma unroll
    for (int j = 0; j < 4; j++) {
        int col = n0 + wc * 64 + j * 16 + ln15;
        float cbv = ldin(cb, l * HD + col, bfv);
#pragma unroll
        for (int i = 0; i < 4; i++) {
            int rg = row0 + wr * 64 + i * 16 + quad * 4;
#pragma unroll
            for (int r = 0; r < 4; r++)
                ybf[(size_t)(rg + r) * HD + col] = __float2bfloat16(acc[i * 4 + j][r] + cbv);
        }
    }
}

// ---------------- LayerNorm + affine + residual ----------------
__global__ __launch_bounds__(256) void k_ln(const __hip_bfloat16* __restrict__ ybf,
                                            const void* __restrict__ g, const void* __restrict__ bb,
                                            float* __restrict__ h, __hip_bfloat16* __restrict__ hbf,
                                            int l, const int* __restrict__ flag) {
    int bf = *flag;
    int row = blockIdx.x;
    int t = threadIdx.x;
    const __hip_bfloat16* yr = ybf + (size_t)row * HD;
    float v0 = b2f(yr[t]), v1 = b2f(yr[t + 256]);
    float s = v0 + v1, q = v0 * v0 + v1 * v1;
#pragma unroll
    for (int o = 32; o > 0; o >>= 1) { s += __shfl_down(s, o); q += __shfl_down(q, o); }
    __shared__ float sm[8];
    __shared__ float mv[2];
    int wid = t >> 6;
    if ((t & 63) == 0) { sm[wid] = s; sm[wid + 4] = q; }
    __syncthreads();
    if (t == 0) {
        float S = sm[0] + sm[1] + sm[2] + sm[3];
        float Q = sm[4] + sm[5] + sm[6] + sm[7];
        float mu = S * (1.f / (float)HD);
        float var = Q * (1.f / (float)HD) - mu * mu;
        mv[0] = mu; mv[1] = rsqrtf(var + LNEPS);
    }
    __syncthreads();
    float mu = mv[0], rs = mv[1];
    float* hr = h + (size_t)row * HD;
    __hip_bfloat16* hbr = hbf + (size_t)row * HD;
    float n0 = (v0 - mu) * rs * ldin(g, l * HD + t, bf)       + ldin(bb, l * HD + t, bf)       + hr[t];
    float n1 = (v1 - mu) * rs * ldin(g, l * HD + t + 256, bf) + ldin(bb, l * HD + t + 256, bf) + hr[t + 256];
    hr[t] = n0;        hbr[t] = __float2bfloat16(n0);
    hr[t + 256] = n1;  hbr[t + 256] = __float2bfloat16(n1);
}

// ---------------- fused output projection ----------------
__global__ __launch_bounds__(256) void k_proj(const float* __restrict__ h,
                                              const float* __restrict__ w1T, const void* __restrict__ b1,
                                              const float* __restrict__ w2T, const void* __restrict__ b2,
                                              const void* __restrict__ w3, const void* __restrict__ b3,
                                              void* __restrict__ out, const int* __restrict__ flag) {
    int bf = *flag;
    int row0 = blockIdx.x * 16;
    int t = threadIdx.x;
    __shared__ float hs[512 * 16];
    __shared__ float o1s[256 * 16];
    __shared__ float o2s[128 * 16];
    for (int e = t; e < 16 * 512; e += 256) {
        int sl = e >> 9, j = e & 511;
        hs[j * 16 + sl] = h[(size_t)(row0 + sl) * HD + j];
    }
    __syncthreads();
    float acc[16];
#pragma unroll
    for (int i = 0; i < 16; i++) acc[i] = 0.f;
    for (int j = 0; j < 512; j++) {
        float w = w1T[j * 256 + t];
#pragma unroll
        for (int sl = 0; sl < 16; sl++) acc[sl] += hs[j * 16 + sl] * w;
    }
    float bb1 = ldin(b1, t, bf);
#pragma unroll
    for (int sl = 0; sl < 16; sl++) o1s[t * 16 + sl] = geluf(acc[sl] + bb1);
    __syncthreads();
    if (t < 128) {
        float a2[16];
#pragma unroll
        for (int i = 0; i < 16; i++) a2[i] = 0.f;
        for (int j = 0; j < 256; j++) {
            float w = w2T[j * 128 + t];
#pragma unroll
            for (int sl = 0; sl < 16; sl++) a2[sl] += o1s[j * 16 + sl] * w;
        }
        float bb2 = ldin(b2, t, bf);
#pragma unroll
        for (int sl = 0; sl < 16; sl++) o2s[t * 16 + sl] = geluf(a2[sl] + bb2);
    }
    __syncthreads();
    if (t < 16) {
        float sum = 0.f;
        for (int j = 0; j < 128; j++) sum += o2s[j * 16 + t] * ldin(w3, j, bf);
        stout(out, row0 + t, sum + ldin(b3, 0, bf), bf);
    }
}

// ---------------- gf = mean over S ----------------
__global__ void k_zero(float* p, int n) {
    int i = blockIdx.x * 256 + threadIdx.x;
    if (i < n) p[i] = 0.f;
}

__global__ __launch_bounds__(512) void k_gf(const float* __restrict__ h, float* __restrict__ gf) {
    int sc = blockIdx.x, b = blockIdx.y;
    int j = threadIdx.x;
    const float* p = h + ((size_t)b * SEQ + sc * 128) * HD + j;
    float s = 0.f;
    for (int i = 0; i < 128; i++) s += p[(size_t)i * HD];
    atomicAdd(&gf[b * HD + j], s * (1.f / (float)SEQ));
}

// ---------------- cryptanalytic head ----------------
__global__ __launch_bounds__(512) void k_head(const float* __restrict__ gf,
                                              const float* __restrict__ h1T, const void* __restrict__ h1b,
                                              const float* __restrict__ h2T, const void* __restrict__ h2b,
                                              void* __restrict__ out, const int* __restrict__ flag) {
    int bf = *flag;
    int b = blockIdx.x;
    int t = threadIdx.x;
    __shared__ float gs[512];
    __shared__ float ks[512];
    gs[t] = gf[b * HD + t];
    __syncthreads();
    float a = 0.f;
    for (int j = 0; j < 512; j++) a += gs[j] * h1T[j * 512 + t];
    ks[t] = geluf(a + ldin(h1b, t, bf));
    __syncthreads();
    if (t < 256) {
        float s = 0.f;
        for (int j = 0; j < 512; j++) s += ks[j] * h2T[j * 256 + t];
        s += ldin(h2b, t, bf);
        stout(out, BB * SEQ + b * NKB + t, 1.f / (1.f + expf(-s)), bf);
    }
}

extern "C" void kernel_launch(void* const* d_in, const int* in_sizes, int n_in,
                              void* d_out, int out_size, void* d_ws, size_t ws_size,
                              hipStream_t stream) {
    const void* x    = d_in[0];
    const void* in_w = d_in[1];
    const void* in_b = d_in[2];
    const void* fwr  = d_in[3];
    const void* fwi  = d_in[4];
    const void* cw   = d_in[5];
    const void* cb   = d_in[6];
    const void* lng  = d_in[7];
    const void* lnb  = d_in[8];
    const void* w1   = d_in[9];
    const void* b1   = d_in[10];
    const void* w2   = d_in[11];
    const void* b2   = d_in[12];
    const void* w3   = d_in[13];
    const void* b3   = d_in[14];
    const void* h1w  = d_in[15];
    const void* h1b  = d_in[16];
    const void* h2w  = d_in[17];
    const void* h2b  = d_in[18];

    float* ws = (float*)d_ws;
    float*          trig = ws;                                  // 131072
    float*          h    = trig + 131072;                       // 8388608
    float*          Xp   = h + 8388608;                         // 4194304 (aliases ybf)
    __hip_bfloat16* ybf  = (__hip_bfloat16*)Xp;                 // 8388608 bf16
    __hip_bfloat16* hbf  = (__hip_bfloat16*)(Xp + 4194304);     // 8388608 bf16 = 4194304 f
    __hip_bfloat16* cwbf = (__hip_bfloat16*)(Xp + 8388608);     // 4194304 bf16 = 2097152 f
    __hip_bfloat16* T2   = (__hip_bfloat16*)(Xp + 10485760);    // 131072 bf16 = 65536 f
    __hip_bfloat16* spec2= (__hip_bfloat16*)(Xp + 10551296);    // 262144 bf16 = 131072 f
    float*          Xft  = Xp + 10682368;                       // 262144
    float*          gf   = Xft + 262144;                        // 4096
    float*          w1T  = gf + 4096;                           // 131072
    float*          w2T  = w1T + 131072;                        // 32768
    float*          h1T  = w2T + 32768;                         // 262144
    float*          h2T  = h1T + 262144;                        // 131072
    int*            flag = (int*)(h2T + 131072);                // 1

    k_flag<<<1, 1, 0, stream>>>((const unsigned int*)lng, flag);
    k_trig<<<256, 256, 0, stream>>>(trig);
    k_t2<<<512, 256, 0, stream>>>(T2);
    k_cwbf<<<8192, 256, 0, stream>>>(cw, cwbf, flag);
    k_tr<<<512, 256, 0, stream>>>(w1, w1T, 8, 512, 131072, flag);
    k_tr<<<128, 256, 0, stream>>>(w2, w2T, 7, 256, 32768, flag);
    k_tr<<<1024, 256, 0, stream>>>(h1w, h1T, 9, 512, 262144, flag);
    k_tr<<<512, 256, 0, stream>>>(h2w, h2T, 8, 512, 131072, flag);
    k_in<<<32768, 256, 0, stream>>>(x, in_w, in_b, h, hbf, flag);

    for (int l = 0; l < LAY; l++) {
        k_dft<<<dim3(16, 2, 8), 256, 0, stream>>>(h, trig, Xp);
        k_dft_red<<<1024, 256, 0, stream>>>(Xp, Xft);
        k_mix<<<dim3(8, 32), 256, 0, stream>>>(Xft, fwr, fwi, spec2, l, flag);
        k_gemm<<<dim3(128, 4), 256, 0, stream>>>(hbf, cwbf, T2, spec2, cb, ybf, l, flag);
        k_ln<<<16384, 256, 0, stream>>>(ybf, lng, lnb, h, hbf, l, flag);
    }

    k_zero<<<16, 256, 0, stream>>>(gf, 4096);
    k_gf<<<dim3(16, 8), 512, 0, stream>>>(h, gf);
    k_proj<<<1024, 256, 0, stream>>>(h, w1T, b1, w2T, b2, w3, b3, d_out, flag);
    k_head<<<8, 512, 0, stream>>>(gf, h1T, h1b, h2T, h2b, d_out, flag);
}